// Round 4
// baseline (772.700 us; speedup 1.0000x reference)
//
#include <hip/hip_runtime.h>
#include <stdint.h>

// Problem constants
#define Bb 2
#define Ss 1024
#define Dd 512
#define Hh 8
#define HD 4096   // Hh*Dd
#define Mm 2048   // Bb*Ss
#define ZCH 2     // z-chunk for energy/attn buffers

typedef _Float16 f16x8 __attribute__((ext_vector_type(8)));
typedef _Float16 f16x4 __attribute__((ext_vector_type(4)));
typedef float    f32x4 __attribute__((ext_vector_type(4)));
typedef short    s16x8 __attribute__((ext_vector_type(8)));

__device__ __forceinline__ float bf2f(unsigned short u) {
    union { uint32_t i; float f; } v; v.i = ((uint32_t)u) << 16; return v.f;
}
__device__ __forceinline__ unsigned short f2bf(float f) {
    union { float f; uint32_t i; } v; v.f = f;
    uint32_t r = v.i + 0x7fffu + ((v.i >> 16) & 1u);
    return (unsigned short)(r >> 16);
}

// ---------------------------------------------------------------------------
// detect_k: decide whether float inputs are fp32 (flag=1) or bf16 (flag=0).
// If x is fp32, every even short is random mantissa bits -> exponent field
// 0xFF appears ~1/256 per short (expect ~32 hits in 16384). Genuine bf16 of
// N(0,1) data never has exponent 0xFF.
// ---------------------------------------------------------------------------
__global__ __launch_bounds__(256) void detect_k(
    const unsigned short* __restrict__ xs, int* __restrict__ flag)
{
    __shared__ int hits;
    if (threadIdx.x == 0) hits = 0;
    __syncthreads();
    int h = 0;
    for (int i = threadIdx.x; i < 16384; i += 256) {
        unsigned short u = xs[i];
        if (((u >> 7) & 0xFF) == 0xFF) h++;
    }
    if (h) atomicAdd(&hits, h);
    __syncthreads();
    if (threadIdx.x == 0) *flag = (hits > 0) ? 1 : 0;
}

// ---------------------------------------------------------------------------
// proj_gemm: C[2048, Ncols](f16) = A[2048,512] @ W[512, ldw](cols wcol0..)
// (+ bias). A/W/bias dtype chosen by *flag (0: bf16, 1: fp32).
// 128x128 block tile, 4 waves, 64x64/wave, mfma_f32_16x16x32_f16.
// ---------------------------------------------------------------------------
__global__ __launch_bounds__(256) void proj_gemm(
    const void* __restrict__ A, const void* __restrict__ W,
    const void* __restrict__ bias, _Float16* __restrict__ C,
    int Ncols, int wcol0, int ldw, const int* __restrict__ flag)
{
    const int f32m = *flag;
    const int lane = threadIdx.x & 63;
    const int wave = threadIdx.x >> 6;
    const int quad = lane >> 4, l15 = lane & 15;
    const int m0 = blockIdx.y * 128 + (wave >> 1) * 64;
    const int n0 = blockIdx.x * 128 + (wave & 1) * 64;

    f32x4 acc[4][4] = {};
    for (int kb = 0; kb < 512; kb += 32) {
        f16x8 af[4], bfr[4];
        if (f32m) {
#pragma unroll
            for (int mi = 0; mi < 4; mi++) {
                const float* ap = (const float*)A + (size_t)(m0 + mi * 16 + l15) * 512 + kb + quad * 8;
                float4 u0 = *(const float4*)ap;
                float4 u1 = *(const float4*)(ap + 4);
                f16x8 t;
                t[0] = (_Float16)u0.x; t[1] = (_Float16)u0.y; t[2] = (_Float16)u0.z; t[3] = (_Float16)u0.w;
                t[4] = (_Float16)u1.x; t[5] = (_Float16)u1.y; t[6] = (_Float16)u1.z; t[7] = (_Float16)u1.w;
                af[mi] = t;
            }
#pragma unroll
            for (int ni = 0; ni < 4; ni++) {
                const float* bp = (const float*)W + (size_t)(kb + quad * 8) * ldw + wcol0 + n0 + ni * 16 + l15;
                f16x8 t;
#pragma unroll
                for (int j = 0; j < 8; j++) t[j] = (_Float16)bp[(size_t)j * ldw];
                bfr[ni] = t;
            }
        } else {
#pragma unroll
            for (int mi = 0; mi < 4; mi++) {
                s16x8 u = *(const s16x8*)((const unsigned short*)A + (size_t)(m0 + mi * 16 + l15) * 512 + kb + quad * 8);
                f16x8 t;
#pragma unroll
                for (int j = 0; j < 8; j++) t[j] = (_Float16)bf2f((unsigned short)u[j]);
                af[mi] = t;
            }
#pragma unroll
            for (int ni = 0; ni < 4; ni++) {
                const unsigned short* bp = (const unsigned short*)W + (size_t)(kb + quad * 8) * ldw + wcol0 + n0 + ni * 16 + l15;
                f16x8 t;
#pragma unroll
                for (int j = 0; j < 8; j++) t[j] = (_Float16)bf2f(bp[(size_t)j * ldw]);
                bfr[ni] = t;
            }
        }
#pragma unroll
        for (int mi = 0; mi < 4; mi++)
#pragma unroll
            for (int ni = 0; ni < 4; ni++)
                acc[mi][ni] = __builtin_amdgcn_mfma_f32_16x16x32_f16(af[mi], bfr[ni], acc[mi][ni], 0, 0, 0);
    }

#pragma unroll
    for (int mi = 0; mi < 4; mi++) {
#pragma unroll
        for (int ni = 0; ni < 4; ni++) {
            const int cl = n0 + ni * 16 + l15;       // local col
            const int cg = wcol0 + cl;               // global col (for bias)
            float bv = 0.0f;
            if (bias) bv = f32m ? ((const float*)bias)[cg] : bf2f(((const unsigned short*)bias)[cg]);
#pragma unroll
            for (int r = 0; r < 4; r++) {
                const int row = m0 + mi * 16 + quad * 4 + r;
                C[(size_t)row * Ncols + cl] = (_Float16)(acc[mi][ni][r] + bv);
            }
        }
    }
}

// ---------------------------------------------------------------------------
// energy_gemm: z = z0+blockIdx.z (z=h*2+b): E[s,t] = sum_c q[s,c]*k[t,c];
// masked column -> -1e30. q/k are f16 workspace, row stride ldq, head-local
// column offset (h-h0)*512. E indexed by local z.
// ---------------------------------------------------------------------------
__global__ __launch_bounds__(256) void energy_gemm(
    const _Float16* __restrict__ Q, const _Float16* __restrict__ Kb,
    const int* __restrict__ mask, float* __restrict__ E,
    int z0, int h0, int ldq)
{
    const int z = z0 + blockIdx.z;
    const int h = z >> 1, b = z & 1, hloc = h - h0;
    const _Float16* qz = Q + (size_t)b * Ss * ldq + hloc * Dd;
    const _Float16* kz = Kb + (size_t)b * Ss * ldq + hloc * Dd;
    float* Ez = E + (size_t)blockIdx.z * Ss * Ss;

    const int lane = threadIdx.x & 63;
    const int wave = threadIdx.x >> 6;
    const int quad = lane >> 4, l15 = lane & 15;
    const int m0 = blockIdx.y * 128 + (wave >> 1) * 64;   // s
    const int n0 = blockIdx.x * 128 + (wave & 1) * 64;    // t

    f32x4 acc[4][4] = {};
    for (int kb = 0; kb < Dd; kb += 32) {
        f16x8 af[4], bfr[4];
#pragma unroll
        for (int mi = 0; mi < 4; mi++)
            af[mi] = *(const f16x8*)(qz + (size_t)(m0 + mi * 16 + l15) * ldq + kb + quad * 8);
#pragma unroll
        for (int ni = 0; ni < 4; ni++)
            bfr[ni] = *(const f16x8*)(kz + (size_t)(n0 + ni * 16 + l15) * ldq + kb + quad * 8);
#pragma unroll
        for (int mi = 0; mi < 4; mi++)
#pragma unroll
            for (int ni = 0; ni < 4; ni++)
                acc[mi][ni] = __builtin_amdgcn_mfma_f32_16x16x32_f16(af[mi], bfr[ni], acc[mi][ni], 0, 0, 0);
    }

#pragma unroll
    for (int ni = 0; ni < 4; ni++) {
        const int col = n0 + ni * 16 + l15;
        const int keep = mask[col];
#pragma unroll
        for (int mi = 0; mi < 4; mi++) {
#pragma unroll
            for (int r = 0; r < 4; r++) {
                const int row = m0 + mi * 16 + quad * 4 + r;
                Ez[(size_t)row * Ss + col] = keep ? acc[mi][ni][r] : -1e30f;
            }
        }
    }
}

// ---------------------------------------------------------------------------
// softmax over last axis: one 256-thr block per row of 1024 fp32 -> f16 attn.
// ---------------------------------------------------------------------------
__global__ __launch_bounds__(256) void softmax_k(
    const float* __restrict__ E, _Float16* __restrict__ Attn)
{
    const int row = blockIdx.x;
    const float* e = E + (size_t)row * Ss;
    _Float16* a = Attn + (size_t)row * Ss;
    const int tid = threadIdx.x;
    const int wave = tid >> 6, lane = tid & 63;

    float4 ev = *(const float4*)(e + tid * 4);
    float v0 = ev.x, v1 = ev.y, v2 = ev.z, v3 = ev.w;
    float m = fmaxf(fmaxf(v0, v1), fmaxf(v2, v3));
#pragma unroll
    for (int off = 1; off < 64; off <<= 1) m = fmaxf(m, __shfl_xor(m, off));
    __shared__ float sm[4], ssum[4];
    if (lane == 0) sm[wave] = m;
    __syncthreads();
    m = fmaxf(fmaxf(sm[0], sm[1]), fmaxf(sm[2], sm[3]));

    v0 = __expf(v0 - m); v1 = __expf(v1 - m); v2 = __expf(v2 - m); v3 = __expf(v3 - m);
    float s = v0 + v1 + v2 + v3;
#pragma unroll
    for (int off = 1; off < 64; off <<= 1) s += __shfl_xor(s, off);
    if (lane == 0) ssum[wave] = s;
    __syncthreads();
    s = ssum[0] + ssum[1] + ssum[2] + ssum[3];
    const float inv = (s > 0.0f) ? (1.0f / s) : 0.0f;

    f16x4 o;
    o[0] = (_Float16)(v0 * inv); o[1] = (_Float16)(v1 * inv);
    o[2] = (_Float16)(v2 * inv); o[3] = (_Float16)(v3 * inv);
    *(f16x4*)(a + tid * 4) = o;
}

// ---------------------------------------------------------------------------
// pv_gemm: z = z0+blockIdx.z: out[t,c] = sum_s attn[s,t]*v[s,c]  (A^T V),
// epilogue (g*acc + xp[b,t,c])/(g+1) -> d_out (fp32 or bf16 per flag).
// ---------------------------------------------------------------------------
__global__ __launch_bounds__(256) void pv_gemm(
    const _Float16* __restrict__ At, const _Float16* __restrict__ V,
    const _Float16* __restrict__ Xp, const void* __restrict__ G,
    void* __restrict__ Out, int z0, int h0, int ldv,
    const int* __restrict__ flag)
{
    const int f32m = *flag;
    const int z = z0 + blockIdx.z;
    const int h = z >> 1, b = z & 1, hloc = h - h0;
    const _Float16* az = At + (size_t)blockIdx.z * Ss * Ss;
    const _Float16* vz = V + (size_t)b * Ss * ldv + hloc * Dd;

    const int lane = threadIdx.x & 63;
    const int wave = threadIdx.x >> 6;
    const int quad = lane >> 4, l15 = lane & 15;
    const int m0 = blockIdx.y * 128 + (wave >> 1) * 64;   // t
    const int n0 = blockIdx.x * 128 + (wave & 1) * 64;    // c

    f32x4 acc[4][4] = {};
    for (int kk = 0; kk < Ss; kk += 32) {
        f16x8 af[4], bfr[4];
#pragma unroll
        for (int mi = 0; mi < 4; mi++) {
            const _Float16* ap = az + (size_t)(kk + quad * 8) * Ss + m0 + mi * 16 + l15;
            f16x8 t;
#pragma unroll
            for (int j = 0; j < 8; j++) t[j] = ap[(size_t)j * Ss];
            af[mi] = t;
        }
#pragma unroll
        for (int ni = 0; ni < 4; ni++) {
            const _Float16* bp = vz + (size_t)(kk + quad * 8) * ldv + n0 + ni * 16 + l15;
            f16x8 t;
#pragma unroll
            for (int j = 0; j < 8; j++) t[j] = bp[(size_t)j * ldv];
            bfr[ni] = t;
        }
#pragma unroll
        for (int mi = 0; mi < 4; mi++)
#pragma unroll
            for (int ni = 0; ni < 4; ni++)
                acc[mi][ni] = __builtin_amdgcn_mfma_f32_16x16x32_f16(af[mi], bfr[ni], acc[mi][ni], 0, 0, 0);
    }

    const float g = f32m ? ((const float*)G)[h] : bf2f(((const unsigned short*)G)[h]);
    const float inv = 1.0f / (g + 1.0f);
#pragma unroll
    for (int mi = 0; mi < 4; mi++) {
#pragma unroll
        for (int ni = 0; ni < 4; ni++) {
            const int c = n0 + ni * 16 + l15;
#pragma unroll
            for (int r = 0; r < 4; r++) {
                const int t = m0 + mi * 16 + quad * 4 + r;
                const float xpv = (float)Xp[(size_t)(b * Ss + t) * Dd + c];
                const float val = (g * acc[mi][ni][r] + xpv) * inv;
                const size_t oi = (size_t)((b * Hh + h) * Ss + t) * Dd + c;
                if (f32m) ((float*)Out)[oi] = val;
                else      ((unsigned short*)Out)[oi] = f2bf(val);
            }
        }
    }
}

// ---------------------------------------------------------------------------
extern "C" void kernel_launch(void* const* d_in, const int* in_sizes, int n_in,
                              void* d_out, int out_size, void* d_ws, size_t ws_size,
                              hipStream_t stream) {
    const void* x    = d_in[0];
    const void* y    = d_in[1];
    const void* Wq   = d_in[2];
    const void* bq   = d_in[3];
    const void* Wk   = d_in[4];
    const void* bk   = d_in[5];
    const void* Wv   = d_in[6];
    const void* bv   = d_in[7];
    const void* Wp   = d_in[8];
    const void* gm   = d_in[9];
    const int*  mask = (const int*)d_in[10];

    // Heads per outer iteration: full (8) if workspace allows, else per-head.
    // HCH=8 footprint: 4096 + 3*16MiB + 2MiB + 8MiB + 4MiB = 65,015,808 B.
    const int HCH = (ws_size >= (size_t)65015808) ? 8 : 1;
    const int NC  = HCH * Dd;  // q/k/v buffer width

    char* ws = (char*)d_ws;
    int* flag = (int*)ws;
    const size_t QB = (size_t)Mm * NC * 2;           // q/k/v bytes each
    _Float16* qb = (_Float16*)(ws + 4096);
    _Float16* kb = (_Float16*)(ws + 4096 + QB);
    _Float16* vb = (_Float16*)(ws + 4096 + 2 * QB);
    _Float16* xp = (_Float16*)(ws + 4096 + 3 * QB);
    float*    en = (float*)   (ws + 4096 + 3 * QB + (size_t)Mm * Dd * 2);
    _Float16* at = (_Float16*)(ws + 4096 + 3 * QB + (size_t)Mm * Dd * 2
                               + (size_t)ZCH * Ss * Ss * 4);

    dim3 blk(256);
    detect_k<<<1, blk, 0, stream>>>((const unsigned short*)x, flag);

    // xp = x @ Wp (no bias), full 512 cols
    proj_gemm<<<dim3(Dd / 128, Mm / 128), blk, 0, stream>>>(
        x, Wp, nullptr, xp, Dd, 0, Dd, flag);

    for (int h0 = 0; h0 < Hh; h0 += HCH) {
        dim3 pg(NC / 128, Mm / 128);
        proj_gemm<<<pg, blk, 0, stream>>>(x, Wq, bq, qb, NC, h0 * Dd, HD, flag);
        proj_gemm<<<pg, blk, 0, stream>>>(y, Wk, bk, kb, NC, h0 * Dd, HD, flag);
        proj_gemm<<<pg, blk, 0, stream>>>(y, Wv, bv, vb, NC, h0 * Dd, HD, flag);

        for (int z0 = 2 * h0; z0 < 2 * (h0 + HCH); z0 += ZCH) {
            energy_gemm<<<dim3(Ss / 128, Ss / 128, ZCH), blk, 0, stream>>>(
                qb, kb, mask, en, z0, h0, NC);
            softmax_k<<<dim3(ZCH * Ss), blk, 0, stream>>>(en, at);
            pv_gemm<<<dim3(Dd / 128, Ss / 128, ZCH), blk, 0, stream>>>(
                at, vb, xp, gm, d_out, z0, h0, NC, flag);
        }
    }
}

// Round 5
// 345.394 us; speedup vs baseline: 2.2372x; 2.2372x over previous
//
#include <hip/hip_runtime.h>
#include <stdint.h>

// Problem constants (fp32 inputs/outputs — confirmed by round-4 pass)
#define Bb 2
#define Ss 1024
#define Dd 512
#define Hh 8
#define HD 4096   // Hh*Dd
#define Mm 2048   // Bb*Ss

typedef _Float16 f16x8 __attribute__((ext_vector_type(8)));
typedef _Float16 f16x4 __attribute__((ext_vector_type(4)));
typedef float    f32x4 __attribute__((ext_vector_type(4)));

// ---------------------------------------------------------------------------
// cvt_f16: fp32 -> f16 elementwise (x/y staging). n multiple of 1024.
// ---------------------------------------------------------------------------
__global__ __launch_bounds__(256) void cvt_f16(
    const float* __restrict__ in, _Float16* __restrict__ out, int n)
{
    int i = (blockIdx.x * 256 + threadIdx.x) * 4;
    if (i < n) {
        float4 u = *(const float4*)(in + i);
        f16x4 o;
        o[0] = (_Float16)u.x; o[1] = (_Float16)u.y;
        o[2] = (_Float16)u.z; o[3] = (_Float16)u.w;
        *(f16x4*)(out + i) = o;
    }
}

// ---------------------------------------------------------------------------
// cvt_w_pk: W fp32 [512][ld], cols [col0, col0+NC) -> f16 k-pack8:
//   out[((k/8)*NC + n)*8 + (k%8)]
// grid (NC/256, 64). Reads coalesced (lanes = consecutive n), 16B stores.
// ---------------------------------------------------------------------------
__global__ __launch_bounds__(256) void cvt_w_pk(
    const float* __restrict__ W, int ld, int col0,
    _Float16* __restrict__ out, int NC)
{
    const int n  = blockIdx.x * 256 + threadIdx.x;
    const int k0 = blockIdx.y * 8;
    f16x8 o;
#pragma unroll
    for (int j = 0; j < 8; j++)
        o[j] = (_Float16)W[(size_t)(k0 + j) * ld + col0 + n];
    *(f16x8*)(out + ((size_t)(k0 >> 3) * NC + n) * 8) = o;
}

// ---------------------------------------------------------------------------
// proj_f16: C[2048, NC] = A[2048,512](f16) @ Wpk(k-pack8) + bias(fp32).
// 128x128 block tile, 4 waves, 64x64/wave, mfma 16x16x32 f16.
// packC=0: C row-major f16; packC=1: C k-pack8 over rows (for V).
// ---------------------------------------------------------------------------
__global__ __launch_bounds__(256) void proj_f16(
    const _Float16* __restrict__ A, const _Float16* __restrict__ Wpk,
    const float* __restrict__ bias, int bias0,
    _Float16* __restrict__ C, int NC, int packC)
{
    const int lane = threadIdx.x & 63;
    const int wave = threadIdx.x >> 6;
    const int quad = lane >> 4, l15 = lane & 15;
    const int m0 = blockIdx.y * 128 + (wave >> 1) * 64;
    const int n0 = blockIdx.x * 128 + (wave & 1) * 64;

    f32x4 acc[4][4] = {};
    for (int kb = 0; kb < 512; kb += 32) {
        f16x8 af[4], bf[4];
#pragma unroll
        for (int mi = 0; mi < 4; mi++)
            af[mi] = *(const f16x8*)(A + (size_t)(m0 + mi * 16 + l15) * 512 + kb + quad * 8);
#pragma unroll
        for (int ni = 0; ni < 4; ni++)
            bf[ni] = *(const f16x8*)(Wpk + ((size_t)((kb >> 3) + quad) * NC + n0 + ni * 16 + l15) * 8);
#pragma unroll
        for (int mi = 0; mi < 4; mi++)
#pragma unroll
            for (int ni = 0; ni < 4; ni++)
                acc[mi][ni] = __builtin_amdgcn_mfma_f32_16x16x32_f16(af[mi], bf[ni], acc[mi][ni], 0, 0, 0);
    }

#pragma unroll
    for (int mi = 0; mi < 4; mi++) {
#pragma unroll
        for (int ni = 0; ni < 4; ni++) {
            const int col = n0 + ni * 16 + l15;
            const float bv = bias ? bias[bias0 + col] : 0.0f;
#pragma unroll
            for (int r = 0; r < 4; r++) {
                const int row = m0 + mi * 16 + quad * 4 + r;
                const _Float16 val = (_Float16)(acc[mi][ni][r] + bv);
                if (packC)
                    C[((size_t)(row >> 3) * NC + col) * 8 + (row & 7)] = val;
                else
                    C[(size_t)row * NC + col] = val;
            }
        }
    }
}

// ---------------------------------------------------------------------------
// energy_f16: zl = blockIdx.z in [0, 2*HG): global z = 2*h0 + zl.
// E[s,t] = sum_c q[s,c]*k[t,c]; masked col -> -30000 (f16 sentinel).
// q,k row-major f16 [b*Ss+s][NC], head cols (zl>>1)*512.
// ---------------------------------------------------------------------------
__global__ __launch_bounds__(256) void energy_f16(
    const _Float16* __restrict__ Q, const _Float16* __restrict__ Kb,
    const int* __restrict__ mask, _Float16* __restrict__ E, int NC)
{
    const int zl = blockIdx.z;
    const int b = zl & 1, hloc = zl >> 1;
    const _Float16* qz = Q + (size_t)b * Ss * NC + hloc * Dd;
    const _Float16* kz = Kb + (size_t)b * Ss * NC + hloc * Dd;
    _Float16* Ez = E + (size_t)zl * Ss * Ss;

    const int lane = threadIdx.x & 63;
    const int wave = threadIdx.x >> 6;
    const int quad = lane >> 4, l15 = lane & 15;
    const int m0 = blockIdx.y * 128 + (wave >> 1) * 64;   // s
    const int n0 = blockIdx.x * 128 + (wave & 1) * 64;    // t

    f32x4 acc[4][4] = {};
    for (int kb = 0; kb < Dd; kb += 32) {
        f16x8 af[4], bf[4];
#pragma unroll
        for (int mi = 0; mi < 4; mi++)
            af[mi] = *(const f16x8*)(qz + (size_t)(m0 + mi * 16 + l15) * NC + kb + quad * 8);
#pragma unroll
        for (int ni = 0; ni < 4; ni++)
            bf[ni] = *(const f16x8*)(kz + (size_t)(n0 + ni * 16 + l15) * NC + kb + quad * 8);
#pragma unroll
        for (int mi = 0; mi < 4; mi++)
#pragma unroll
            for (int ni = 0; ni < 4; ni++)
                acc[mi][ni] = __builtin_amdgcn_mfma_f32_16x16x32_f16(af[mi], bf[ni], acc[mi][ni], 0, 0, 0);
    }

#pragma unroll
    for (int ni = 0; ni < 4; ni++) {
        const int col = n0 + ni * 16 + l15;
        const int keep = mask[col];
#pragma unroll
        for (int mi = 0; mi < 4; mi++) {
#pragma unroll
            for (int r = 0; r < 4; r++) {
                const int row = m0 + mi * 16 + quad * 4 + r;
                Ez[(size_t)row * Ss + col] = keep ? (_Float16)acc[mi][ni][r]
                                                  : (_Float16)(-30000.0f);
            }
        }
    }
}

// ---------------------------------------------------------------------------
// softmax_pk: one block = 8 consecutive global rows (one k-group) x 1024 t.
// Thread tid holds 4 t-values x 8 rows in registers. Output written k-pack8:
//   at[((grow/8)*1024 + t)*8 + (grow%8)]  -> 16B f16x8 stores, coalesced.
// ---------------------------------------------------------------------------
__global__ __launch_bounds__(256) void softmax_pk(
    const _Float16* __restrict__ E, _Float16* __restrict__ At)
{
    const int rb = blockIdx.x;                       // row-group (8 rows)
    const _Float16* e0 = E + (size_t)rb * 8 * Ss;
    const int tid = threadIdx.x;
    const int wave = tid >> 6, lane = tid & 63;
    const int t0 = tid * 4;

    float v[8][4];
#pragma unroll
    for (int r = 0; r < 8; r++) {
        f16x4 u = *(const f16x4*)(e0 + (size_t)r * Ss + t0);
#pragma unroll
        for (int j = 0; j < 4; j++) v[r][j] = (float)u[j];
    }

    __shared__ float red[4][8];
    // ---- block max per row ----
    float mx[8];
#pragma unroll
    for (int r = 0; r < 8; r++) {
        float lm = fmaxf(fmaxf(v[r][0], v[r][1]), fmaxf(v[r][2], v[r][3]));
#pragma unroll
        for (int off = 1; off < 64; off <<= 1) lm = fmaxf(lm, __shfl_xor(lm, off));
        mx[r] = lm;
    }
    if (lane == 0) {
#pragma unroll
        for (int r = 0; r < 8; r++) red[wave][r] = mx[r];
    }
    __syncthreads();
#pragma unroll
    for (int r = 0; r < 8; r++)
        mx[r] = fmaxf(fmaxf(red[0][r], red[1][r]), fmaxf(red[2][r], red[3][r]));
    __syncthreads();

    // ---- exp + block sum per row ----
    float inv[8];
#pragma unroll
    for (int r = 0; r < 8; r++) {
        v[r][0] = __expf(v[r][0] - mx[r]); v[r][1] = __expf(v[r][1] - mx[r]);
        v[r][2] = __expf(v[r][2] - mx[r]); v[r][3] = __expf(v[r][3] - mx[r]);
        float ls = (v[r][0] + v[r][1]) + (v[r][2] + v[r][3]);
#pragma unroll
        for (int off = 1; off < 64; off <<= 1) ls += __shfl_xor(ls, off);
        inv[r] = ls;
    }
    if (lane == 0) {
#pragma unroll
        for (int r = 0; r < 8; r++) red[wave][r] = inv[r];
    }
    __syncthreads();
#pragma unroll
    for (int r = 0; r < 8; r++) {
        const float s = (red[0][r] + red[1][r]) + (red[2][r] + red[3][r]);
        inv[r] = (s > 0.0f) ? (1.0f / s) : 0.0f;
    }

    // ---- packed coalesced write ----
    _Float16* ob = At + (size_t)rb * Ss * 8;
#pragma unroll
    for (int j = 0; j < 4; j++) {
        f16x8 o;
#pragma unroll
        for (int r = 0; r < 8; r++) o[r] = (_Float16)(v[r][j] * inv[r]);
        *(f16x8*)(ob + (size_t)(t0 + j) * 8) = o;
    }
}

// ---------------------------------------------------------------------------
// pv_f16: out[t,c] = sum_s P[s,t]*v[s,c]  (A^T V) with both operands k-pack8
// -> all 16B vector frag loads. Epilogue (g*acc + xp)/(g+1) -> fp32 d_out.
// ---------------------------------------------------------------------------
__global__ __launch_bounds__(256) void pv_f16(
    const _Float16* __restrict__ At, const _Float16* __restrict__ Vpk,
    const _Float16* __restrict__ Xp, const float* __restrict__ G,
    float* __restrict__ Out, int h0, int NC)
{
    const int zl = blockIdx.z;
    const int b = zl & 1, hloc = zl >> 1;
    const int h = h0 + hloc;
    const _Float16* az = At + (size_t)zl * Ss * Ss;   // k-pack8 per z-slice

    const int lane = threadIdx.x & 63;
    const int wave = threadIdx.x >> 6;
    const int quad = lane >> 4, l15 = lane & 15;
    const int m0 = blockIdx.y * 128 + (wave >> 1) * 64;   // t
    const int n0 = blockIdx.x * 128 + (wave & 1) * 64;    // c (local 0..512)

    f32x4 acc[4][4] = {};
    for (int kb = 0; kb < Ss; kb += 32) {
        f16x8 af[4], bf[4];
#pragma unroll
        for (int mi = 0; mi < 4; mi++)
            af[mi] = *(const f16x8*)(az + ((size_t)((kb >> 3) + quad) * Ss + m0 + mi * 16 + l15) * 8);
#pragma unroll
        for (int ni = 0; ni < 4; ni++)
            bf[ni] = *(const f16x8*)(Vpk + ((size_t)(((b * Ss + kb) >> 3) + quad) * NC
                                            + hloc * Dd + n0 + ni * 16 + l15) * 8);
#pragma unroll
        for (int mi = 0; mi < 4; mi++)
#pragma unroll
            for (int ni = 0; ni < 4; ni++)
                acc[mi][ni] = __builtin_amdgcn_mfma_f32_16x16x32_f16(af[mi], bf[ni], acc[mi][ni], 0, 0, 0);
    }

    const float g = G[h];
    const float inv = 1.0f / (g + 1.0f);
#pragma unroll
    for (int mi = 0; mi < 4; mi++) {
#pragma unroll
        for (int ni = 0; ni < 4; ni++) {
            const int c = n0 + ni * 16 + l15;
#pragma unroll
            for (int r = 0; r < 4; r++) {
                const int t = m0 + mi * 16 + quad * 4 + r;
                const float xpv = (float)Xp[(size_t)(b * Ss + t) * Dd + c];
                Out[(size_t)((b * Hh + h) * Ss + t) * Dd + c] =
                    (g * acc[mi][ni][r] + xpv) * inv;
            }
        }
    }
}

// ---------------------------------------------------------------------------
// Workspace (HG=4, guaranteed fit in 62 MiB; HG=8 if ws >= 128 MiB):
//   Wbuf  512*NC f16          (k-pack8 staging, reused per weight)
//   q, k  [2048][NC] f16 row-major
//   v     [2048][NC] f16 k-pack8 over rows
//   xp    [2048][512] f16
//   en    [2*HG][1024][1024] f16       (xf/yf staging aliases its head)
//   at    [2*HG] k-pack8 f16
// ---------------------------------------------------------------------------
extern "C" void kernel_launch(void* const* d_in, const int* in_sizes, int n_in,
                              void* d_out, int out_size, void* d_ws, size_t ws_size,
                              hipStream_t stream) {
    const float* x    = (const float*)d_in[0];
    const float* y    = (const float*)d_in[1];
    const float* Wq   = (const float*)d_in[2];
    const float* bq   = (const float*)d_in[3];
    const float* Wk   = (const float*)d_in[4];
    const float* bk   = (const float*)d_in[5];
    const float* Wv   = (const float*)d_in[6];
    const float* bv   = (const float*)d_in[7];
    const float* Wp   = (const float*)d_in[8];
    const float* gm   = (const float*)d_in[9];
    const int*   mask = (const int*)d_in[10];

    const int HG = (ws_size >= (size_t)134217728) ? 8 : 4;   // heads per group
    const int NC = HG * Dd;
    const int NZ = 2 * HG;                                    // z per group

    char* ws = (char*)d_ws;
    size_t off = 0;
    _Float16* Wbuf = (_Float16*)(ws + off); off += (size_t)512 * NC * 2;
    _Float16* qb   = (_Float16*)(ws + off); off += (size_t)Mm * NC * 2;
    _Float16* kb   = (_Float16*)(ws + off); off += (size_t)Mm * NC * 2;
    _Float16* vb   = (_Float16*)(ws + off); off += (size_t)Mm * NC * 2;
    _Float16* xp   = (_Float16*)(ws + off); off += (size_t)Mm * Dd * 2;
    _Float16* en   = (_Float16*)(ws + off); off += (size_t)NZ * Ss * Ss * 2;
    _Float16* at   = (_Float16*)(ws + off);
    _Float16* xf   = en;                      // staging inside en region
    _Float16* yf   = en + (size_t)Mm * 512;   // (4 MiB << en size)

    dim3 blk(256);
    const int NXY = Mm * 512;

    // xp = x @ Wp (no bias)
    cvt_f16<<<dim3(NXY / 1024), blk, 0, stream>>>(x, xf, NXY);
    cvt_w_pk<<<dim3(2, 64), blk, 0, stream>>>(Wp, Dd, 0, Wbuf, Dd);
    proj_f16<<<dim3(4, 16), blk, 0, stream>>>(xf, Wbuf, nullptr, 0, xp, Dd, 0);

    for (int h0 = 0; h0 < Hh; h0 += HG) {
        // re-stage x/y (en region was clobbered by previous group's energy)
        cvt_f16<<<dim3(NXY / 1024), blk, 0, stream>>>(x, xf, NXY);
        cvt_f16<<<dim3(NXY / 1024), blk, 0, stream>>>(y, yf, NXY);

        cvt_w_pk<<<dim3(NC / 256, 64), blk, 0, stream>>>(Wq, HD, h0 * Dd, Wbuf, NC);
        proj_f16<<<dim3(NC / 128, 16), blk, 0, stream>>>(xf, Wbuf, bq, h0 * Dd, qb, NC, 0);
        cvt_w_pk<<<dim3(NC / 256, 64), blk, 0, stream>>>(Wk, HD, h0 * Dd, Wbuf, NC);
        proj_f16<<<dim3(NC / 128, 16), blk, 0, stream>>>(yf, Wbuf, bk, h0 * Dd, kb, NC, 0);
        cvt_w_pk<<<dim3(NC / 256, 64), blk, 0, stream>>>(Wv, HD, h0 * Dd, Wbuf, NC);
        proj_f16<<<dim3(NC / 128, 16), blk, 0, stream>>>(yf, Wbuf, bv, h0 * Dd, vb, NC, 1);

        energy_f16<<<dim3(8, 8, NZ), blk, 0, stream>>>(qb, kb, mask, en, NC);
        softmax_pk<<<dim3(NZ * Ss / 8), blk, 0, stream>>>(en, at);
        pv_f16<<<dim3(4, 8, NZ), blk, 0, stream>>>(at, vb, xp, gm, (float*)d_out, h0, NC);
    }
}